// Round 2
// baseline (187.951 us; speedup 1.0000x reference)
//
#include <hip/hip_runtime.h>
#include <hip/hip_bf16.h>

#define EPSV 1e-5f
#define NPATCH 32768   // 32 images * 32 * 32 patches

// One wave per patch. Lane owns input elements e = i*256 + lane*4 + j (i<3,j<4).
// w1 (16ch x 768) held entirely in VGPRs: 192 floats/lane.
__global__ __launch_bounds__(256, 2)
void cnn16_fused(const float* __restrict__ in,
                 const float* __restrict__ w1, const float* __restrict__ b1,
                 const float* __restrict__ g1, const float* __restrict__ bt1,
                 const float* __restrict__ m1, const float* __restrict__ v1,
                 const float* __restrict__ w2, const float* __restrict__ b2,
                 const float* __restrict__ g2, const float* __restrict__ bt2,
                 const float* __restrict__ m2, const float* __restrict__ v2,
                 const float* __restrict__ w3, const float* __restrict__ b3,
                 float* __restrict__ out)
{
    const int lane = threadIdx.x & 63;
    const int wid  = (blockIdx.x << 2) + (threadIdx.x >> 6);
    const int nw   = gridDim.x << 2;

    // ---- prologue: conv1 weights into registers (coalesced float4) ----
    float4 wr[16][3];
#pragma unroll
    for (int c = 0; c < 16; ++c)
#pragma unroll
        for (int i = 0; i < 3; ++i)
            wr[c][i] = *reinterpret_cast<const float4*>(w1 + c * 768 + i * 256 + (lane << 2));

    // lane's spatial offset inside the patch: e=i*256+lane*4+j -> ci=i, kh=lane>>2, kw=(lane&3)*4+j
    const int off0 = (lane >> 2) * 512 + (lane & 3) * 4;

    // per-lane channel (for conv1/BN1 stage): c = lane & 15
    const int cl = lane & 15;
    const float inv1 = g1[cl] * rsqrtf(v1[cl] + EPSV);
    const float bb1  = (b1[cl] - m1[cl]) * inv1 + bt1[cl];   // (conv+b1)*inv1 + beta1 - m1*inv1

    float w2v[4], A2[4], B2[4], w3v[4];
#pragma unroll
    for (int o = 0; o < 4; ++o) {
        w2v[o] = w2[o * 16 + cl];
        const float iv = g2[o] * rsqrtf(v2[o] + EPSV);
        A2[o] = iv;
        B2[o] = (b2[o] - m2[o]) * iv + bt2[o];
        w3v[o] = w3[o];
    }
    const float bias3 = b3[0];

    const bool hi1 = (lane & 1) != 0;
    const bool hi2 = (lane & 2) != 0;
    const bool hi4 = (lane & 4) != 0;
    const bool hi8 = (lane & 8) != 0;

    for (int p = wid; p < NPATCH; p += nw) {
        const int b  = p >> 10;
        const int ph = (p >> 5) & 31;
        const int pw = p & 31;

        const float* base = in + b * 786432 + ph * 8192 + pw * 16 + off0;
        float4 x0 = *reinterpret_cast<const float4*>(base);
        float4 x1 = *reinterpret_cast<const float4*>(base + 262144);
        float4 x2 = *reinterpret_cast<const float4*>(base + 524288);

        // per-lane partial dot for each of the 16 channels
        float acc[16];
#pragma unroll
        for (int c = 0; c < 16; ++c) {
            float a = 0.f;
            a = fmaf(x0.x, wr[c][0].x, a); a = fmaf(x0.y, wr[c][0].y, a);
            a = fmaf(x0.z, wr[c][0].z, a); a = fmaf(x0.w, wr[c][0].w, a);
            a = fmaf(x1.x, wr[c][1].x, a); a = fmaf(x1.y, wr[c][1].y, a);
            a = fmaf(x1.z, wr[c][1].z, a); a = fmaf(x1.w, wr[c][1].w, a);
            a = fmaf(x2.x, wr[c][2].x, a); a = fmaf(x2.y, wr[c][2].y, a);
            a = fmaf(x2.z, wr[c][2].z, a); a = fmaf(x2.w, wr[c][2].w, a);
            acc[c] = a;
        }

        // log-fold reduction: after masks 1,2,4,8 lane l holds channel (l&15)
        // summed over its 16-lane group; masks 16,32 finish the 64-lane sum.
        float t8[8];
#pragma unroll
        for (int j = 0; j < 8; ++j) {
            const float keep = hi1 ? acc[2 * j + 1] : acc[2 * j];
            const float send = hi1 ? acc[2 * j] : acc[2 * j + 1];
            t8[j] = keep + __shfl_xor(send, 1, 64);
        }
        float t4[4];
#pragma unroll
        for (int j = 0; j < 4; ++j) {
            const float keep = hi2 ? t8[2 * j + 1] : t8[2 * j];
            const float send = hi2 ? t8[2 * j] : t8[2 * j + 1];
            t4[j] = keep + __shfl_xor(send, 2, 64);
        }
        float t2[2];
#pragma unroll
        for (int j = 0; j < 2; ++j) {
            const float keep = hi4 ? t4[2 * j + 1] : t4[2 * j];
            const float send = hi4 ? t4[2 * j] : t4[2 * j + 1];
            t2[j] = keep + __shfl_xor(send, 4, 64);
        }
        {
            const float keep = hi8 ? t2[1] : t2[0];
            const float send = hi8 ? t2[0] : t2[1];
            t2[0] = keep + __shfl_xor(send, 8, 64);
        }
        float convc = t2[0];
        convc += __shfl_xor(convc, 16, 64);
        convc += __shfl_xor(convc, 32, 64);   // full conv sum for channel cl

        // BN1 + ReLU (lane's channel)
        float y = fmaf(convc, inv1, bb1);
        y = fmaxf(y, 0.f);

        // 1x1 conv 16->4: butterfly-sum over the 16-lane group (all channels)
        float s = bias3;
#pragma unroll
        for (int o = 0; o < 4; ++o) {
            float z = y * w2v[o];
            z += __shfl_xor(z, 1, 64);
            z += __shfl_xor(z, 2, 64);
            z += __shfl_xor(z, 4, 64);
            z += __shfl_xor(z, 8, 64);
            z = fmaf(z, A2[o], B2[o]);   // BN2
            z = fmaxf(z, 0.f);           // ReLU
            s = fmaf(z, w3v[o], s);      // 1x1 conv 4->1
        }

        // 16x nearest upsample: each lane writes 4 consecutive fp32 pixels (16B)
        const int r  = lane >> 2;
        const int c4 = (lane & 3) << 2;
        float* optr = out + b * 262144 + (ph * 16 + r) * 512 + pw * 16 + c4;
        float4 v4; v4.x = s; v4.y = s; v4.z = s; v4.w = s;
        *reinterpret_cast<float4*>(optr) = v4;
    }
}

extern "C" void kernel_launch(void* const* d_in, const int* in_sizes, int n_in,
                              void* d_out, int out_size, void* d_ws, size_t ws_size,
                              hipStream_t stream) {
    const float* in  = (const float*)d_in[0];
    const float* w1  = (const float*)d_in[1];
    const float* b1  = (const float*)d_in[2];
    const float* g1  = (const float*)d_in[3];
    const float* bt1 = (const float*)d_in[4];
    const float* m1  = (const float*)d_in[5];
    const float* v1  = (const float*)d_in[6];
    const float* w2  = (const float*)d_in[7];
    const float* b2  = (const float*)d_in[8];
    const float* g2  = (const float*)d_in[9];
    const float* bt2 = (const float*)d_in[10];
    const float* m2  = (const float*)d_in[11];
    const float* v2  = (const float*)d_in[12];
    const float* w3  = (const float*)d_in[13];
    const float* b3  = (const float*)d_in[14];
    float* out = (float*)d_out;

    cnn16_fused<<<dim3(512), dim3(256), 0, stream>>>(
        in, w1, b1, g1, bt1, m1, v1, w2, b2, g2, bt2, m2, v2, w3, b3, out);
}